// Round 16
// baseline (42.371 us; speedup 1.0000x reference)
//
#include <hip/hip_runtime.h>

#define NH 4
#define DK 16
#define HD 64
#define CQ 256
#define W 4096
#define BN 4

typedef unsigned short u16;
typedef unsigned int u32;
typedef __attribute__((ext_vector_type(8))) short bf16x8;
typedef __attribute__((ext_vector_type(4))) float f32x4;
typedef __attribute__((ext_vector_type(16))) float f32x16;
typedef __fp16 h2 __attribute__((ext_vector_type(2)));

__device__ inline u32 pkbf(float a, float b) {
    u32 r;
    asm("v_cvt_pk_bf16_f32 %0, %1, %2" : "=v"(r) : "v"(a), "v"(b));
    return r;
}
__device__ inline float bf2f(u16 h) { return __uint_as_float(((unsigned)h) << 16); }
__device__ inline u16 f2bf(float f) {
    unsigned int u = __float_as_uint(f);
    return (u16)((u + 0x7FFFu + ((u >> 16) & 1u)) >> 16);
}
// v_pk_add_f16 with VOP3P clamp: result clamped to [0,1] - the whole sigmoid
__device__ inline h2 pk_add_h2_clamp(h2 a, h2 b) {
    h2 d;
    asm("v_pk_add_f16 %0, %1, %2 clamp" : "=v"(d) : "v"(a), "v"(b));
    return d;
}

#define MFMA(A, B, C) __builtin_amdgcn_mfma_f32_32x32x16_bf16((A), (B), (C), 0, 0, 0)

// ---------------------------------------------------------------------------
// Phase 0: pre-pack weight MFMA A-fragments (96 blocks).
// wq/bq pre-scaled by the hard-sigmoid slope: sigma ~= clamp(s*x+0.5, 0, 1).
// ---------------------------------------------------------------------------
__global__ __launch_bounds__(256) void prep_kernel(
    const float* __restrict__ wq, const float* __restrict__ wk,
    const float* __restrict__ wv, const float* __restrict__ bq,
    u16* __restrict__ wfrag, float* __restrict__ bqs)
{
    const float QS = 0.21f;   // hard-sigmoid slope
    int idx = blockIdx.x * 256 + threadIdx.x;
    for (; idx < 3 * 2 * 16 * 64 * 8; idx += 96 * 256) {
        int j    = idx & 7;
        int lane = (idx >> 3) & 63;
        int s    = (idx >> 9) & 15;
        int ot   = (idx >> 13) & 1;
        int mat  = idx >> 14;
        int o = ot * 32 + (lane & 31);
        int c = s * 16 + (lane >> 5) * 8 + j;
        const float* wsrc = (mat == 0) ? wq : (mat == 1 ? wk : wv);
        float v = wsrc[o * CQ + c];
        if (mat == 0) v *= QS;
        wfrag[idx] = f2bf(v);
    }
    if (blockIdx.x == 0 && threadIdx.x < HD) bqs[threadIdx.x] = bq[threadIdx.x] * 0.21f;
}

// ---------------------------------------------------------------------------
// Phase 1: projections (unchanged, proven ~10us).
// ---------------------------------------------------------------------------
__global__ __launch_bounds__(512, 4) void proj_kernel(
    const float* __restrict__ x_q, const float* __restrict__ x_kv,
    const u16* __restrict__ wfrag, const float* __restrict__ bqs,
    const float* __restrict__ bk, const float* __restrict__ bv,
    u16* __restrict__ qb, u16* __restrict__ kb, u16* __restrict__ vb)
{
    __shared__ __align__(16) u32 xs[2 * 32 * 128];   // 32 KB
    const int tid = threadIdx.x;
    const int b   = blockIdx.x >> 7;
    const int wt  = blockIdx.x & 127;
    const int w0  = wt * 32;

    #pragma unroll
    for (int k = 0; k < 16; ++k) {
        int i  = k * 512 + tid;
        int m  = i >> 12;
        int r  = i & 4095;
        int cp = r >> 5;              // c-pair 0..127
        int w  = r & 31;              // lanes -> consecutive w: coalesced
        const float* src = (m ? x_kv : x_q) + ((size_t)b * CQ + 2 * cp) * W + w0 + w;
        float x0 = src[0];
        float x1 = src[W];
        xs[m * 4096 + w * 128 + (cp ^ ((w & 7) << 2))] = pkbf(x0, x1);
    }
    __syncthreads();

    const int wv_ = tid >> 6;
    if (wv_ < 6) {
        const int lane = tid & 63;
        const int mat  = wv_ >> 1;          // 0 q, 1 k, 2 v
        const int ot   = wv_ & 1;
        const int n    = lane & 31;
        const int khi  = lane >> 5;
        const int m    = (mat == 0) ? 0 : 1;

        const u16* wfp  = wfrag + (((size_t)(mat * 2 + ot) * 16) * 64 + lane) * 8;
        const u32* xrow = xs + m * 4096 + n * 128;
        const int  swz  = (n & 7) << 2;

        const f32x16 z = {0,0,0,0,0,0,0,0,0,0,0,0,0,0,0,0};
        f32x16 acc0 = z, acc1 = z;
        #pragma unroll
        for (int s = 0; s < 16; ++s) {
            const bf16x8 af = *(const bf16x8*)(wfp + s * 512);
            const int cp0 = s * 8 + khi * 4;
            const bf16x8 bf = *(const bf16x8*)(xrow + (cp0 ^ swz));
            if (s & 1) acc1 = MFMA(af, bf, acc1);
            else       acc0 = MFMA(af, bf, acc0);
        }

        const float* bias = (mat == 0) ? bqs : (mat == 1 ? bk : bv);
        u16* dst = (mat == 0) ? qb : (mat == 1 ? kb : vb);
        #pragma unroll
        for (int q = 0; q < 4; ++q) {
            int ob = ot * 32 + 8 * q + 4 * khi;
            float v0 = acc0[4 * q + 0] + acc1[4 * q + 0] + bias[ob + 0];
            float v1 = acc0[4 * q + 1] + acc1[4 * q + 1] + bias[ob + 1];
            float v2 = acc0[4 * q + 2] + acc1[4 * q + 2] + bias[ob + 2];
            float v3 = acc0[4 * q + 3] + acc1[4 * q + 3] + bias[ob + 3];
            int h = ob >> 4, d = ob & 15;
            uint2 pk = make_uint2(pkbf(v0, v1), pkbf(v2, v3));
            *(uint2*)(dst + ((size_t)(b * NH + h) * W + w0 + n) * DK + d) = pk;
        }
    }
}

// ---------------------------------------------------------------------------
// Phase 2: g[k] = sum_q sigma(q.k) fused with partial S = sum_k g[k]*v[k].
// Q PERSISTENT IN REGISTERS: each wave loads its 512-row q-slice once
// (16 x bf16x8 = 64 VGPR), then sweeps 4 k-tiles entirely from registers:
// per k-tile 1 bfrag load + 16 independent MFMA + hard-sigmoid poly.
// Memory ops per MFMA drop 16x -> latency hidden behind ~900cyc compute.
// 1024 blocks x 4 waves = 4096 waves x 64 MFMA.
// ---------------------------------------------------------------------------
__global__ __launch_bounds__(256, 4) void logits_kernel(
    const u16* __restrict__ qb, const u16* __restrict__ kb,
    const u16* __restrict__ vb, float* __restrict__ Spart)
{
    __shared__ float red[4][16];
    const int tid  = threadIdx.x;
    const int wv_  = tid >> 6;
    const int lane = tid & 63;
    const int bh   = blockIdx.x >> 6;
    const int rest = blockIdx.x & 63;    // ktg(0..7)*8 + qs(0..7)
    const int ktg  = rest >> 3;
    const int qs   = rest & 7;
    const int kt0  = ktg * 16 + wv_ * 4; // this wave: k-tiles kt0..kt0+3
    const int r    = lane & 31;
    const int d8   = (lane >> 5) * 8;

    const u16* qp = qb + (((size_t)bh * W + qs * 512 + r) * DK + d8);
    const u16* kp = kb + (((size_t)bh * W + kt0 * 32 + r) * DK + d8);
    const u16* vp = vb + (((size_t)bh * W + kt0 * 32 + r) * DK + d8);

    // persistent q fragments (64 VGPR)
    bf16x8 qreg[16];
    #pragma unroll
    for (int it = 0; it < 16; ++it)
        qreg[it] = *(const bf16x8*)(qp + (size_t)it * 32 * DK);

    const f32x16 z = {0,0,0,0,0,0,0,0,0,0,0,0,0,0,0,0};
    const h2 HALF = {(__fp16)0.5f, (__fp16)0.5f};
    const h2 ONE  = {(__fp16)1.0f, (__fp16)1.0f};

    float p[8];
    #pragma unroll
    for (int j = 0; j < 8; ++j) p[j] = 0.f;

    #pragma unroll
    for (int t = 0; t < 4; ++t) {
        const bf16x8 bfrag = *(const bf16x8*)(kp + (size_t)t * 32 * DK);
        float accA = 0.f, accB = 0.f, accC = 0.f, accD = 0.f;
        #pragma unroll
        for (int it = 0; it < 16; ++it) {
            f32x16 c = MFMA(qreg[it], bfrag, z);
            #pragma unroll
            for (int p2 = 0; p2 < 8; ++p2) {
                h2 u = __builtin_amdgcn_cvt_pkrtz(c[2 * p2], c[2 * p2 + 1]);
                h2 sg = pk_add_h2_clamp(u, HALF);   // sigma = clamp(s*x+0.5)
                switch (p2 & 3) {
                    case 0: accA = __builtin_amdgcn_fdot2(sg, ONE, accA, false); break;
                    case 1: accB = __builtin_amdgcn_fdot2(sg, ONE, accB, false); break;
                    case 2: accC = __builtin_amdgcn_fdot2(sg, ONE, accC, false); break;
                    default: accD = __builtin_amdgcn_fdot2(sg, ONE, accD, false); break;
                }
            }
        }
        float g = (accA + accB) + (accC + accD);
        g += __shfl_xor(g, 32, 64);   // fold the two q-row halves of the column
        bf16x8 v8 = *(const bf16x8*)(vp + (size_t)t * 32 * DK);
        #pragma unroll
        for (int j = 0; j < 8; ++j) p[j] += g * bf2f((u16)v8[j]);
    }

    #pragma unroll
    for (int m = 1; m < 32; m <<= 1) {
        #pragma unroll
        for (int j = 0; j < 8; ++j) p[j] += __shfl_xor(p[j], m, 64);
    }
    if (r == 0) {
        #pragma unroll
        for (int j = 0; j < 8; ++j) red[wv_][d8 + j] = p[j];
    }
    __syncthreads();
    if (tid < 16) {
        float s = (red[0][tid] + red[1][tid]) + (red[2][tid] + red[3][tid]);
        Spart[((size_t)bh * 64 + rest) * 16 + tid] = s;
    }
}

// ---------------------------------------------------------------------------
// Phase 3: reduce Spart (64 partials/bh), scale, output conv. 64 blocks.
// ---------------------------------------------------------------------------
__global__ __launch_bounds__(256) void out_kernel(
    const float* __restrict__ Spart, const float* __restrict__ wo,
    const float* __restrict__ bo, float* __restrict__ out)
{
    __shared__ float red[4][HD];
    __shared__ float pooled[HD];
    const int b  = blockIdx.x >> 4;
    const int og = blockIdx.x & 15;
    const int t  = threadIdx.x;
    const int hd = t & 63;       // (h,d) pair
    const int sg = t >> 6;       // partial segment 0..3
    const int h  = hd >> 4, d = hd & 15;

    const float* sp = Spart + (((size_t)(b * NH + h) * 64) + sg * 16) * 16 + d;
    float s = 0.f;
    #pragma unroll
    for (int i = 0; i < 16; ++i) s += sp[i * 16];
    red[sg][hd] = s;
    __syncthreads();
    if (t < HD)
        pooled[t] = (red[0][t] + red[1][t] + red[2][t] + red[3][t]) *
                    (1.f / ((float)W * (float)W));
    __syncthreads();
    if (t < 16) {
        int o = og * 16 + t;
        float val = bo[o];
        #pragma unroll
        for (int c2 = 0; c2 < HD; ++c2)
            val += wo[o * HD + c2] * pooled[c2];
        out[b * CQ + o] = val;
    }
}

extern "C" void kernel_launch(void* const* d_in, const int* in_sizes, int n_in,
                              void* d_out, int out_size, void* d_ws, size_t ws_size,
                              hipStream_t stream) {
    const float* x_q  = (const float*)d_in[0];
    const float* x_kv = (const float*)d_in[1];
    const float* wq   = (const float*)d_in[2];
    const float* bq   = (const float*)d_in[3];
    const float* wk   = (const float*)d_in[4];
    const float* bk   = (const float*)d_in[5];
    const float* wv   = (const float*)d_in[6];
    const float* bv   = (const float*)d_in[7];
    const float* wo   = (const float*)d_in[8];
    const float* bo   = (const float*)d_in[9];
    float* out = (float*)d_out;

    char* ws = (char*)d_ws;
    u16*   qb    = (u16*)ws;                              // 2 MB
    u16*   kb    = (u16*)(ws + (2u << 20));               // 2 MB
    u16*   vb    = (u16*)(ws + (4u << 20));               // 2 MB (bf16 V)
    float* Spart = (float*)(ws + (6u << 20));             // 64 KB
    u16*   wfrag = (u16*)(ws + (6u << 20) + (256u << 10));// 96 KB
    float* bqs   = (float*)(ws + (6u << 20) + (384u << 10));

    prep_kernel<<<96, 256, 0, stream>>>(wq, wk, wv, bq, wfrag, bqs);
    proj_kernel<<<512, 512, 0, stream>>>(x_q, x_kv, wfrag, bqs, bk, bv, qb, kb, vb);
    logits_kernel<<<1024, 256, 0, stream>>>(qb, kb, vb, Spart);
    out_kernel<<<BN * 16, 256, 0, stream>>>(Spart, wo, bo, out);
}

// Round 17
// 38.780 us; speedup vs baseline: 1.0926x; 1.0926x over previous
//
#include <hip/hip_runtime.h>

#define NH 4
#define DK 16
#define HD 64
#define CQ 256
#define W 4096
#define BN 4

typedef unsigned short u16;
typedef unsigned int u32;
typedef __attribute__((ext_vector_type(8))) short bf16x8;
typedef __attribute__((ext_vector_type(4))) float f32x4;
typedef __attribute__((ext_vector_type(16))) float f32x16;
typedef __fp16 h2 __attribute__((ext_vector_type(2)));

__device__ inline u32 pkbf(float a, float b) {
    u32 r;
    asm("v_cvt_pk_bf16_f32 %0, %1, %2" : "=v"(r) : "v"(a), "v"(b));
    return r;
}
__device__ inline float bf2f(u16 h) { return __uint_as_float(((unsigned)h) << 16); }
__device__ inline u16 f2bf(float f) {
    unsigned int u = __float_as_uint(f);
    return (u16)((u + 0x7FFFu + ((u >> 16) & 1u)) >> 16);
}
// f32 pair -> f16 pair with VOP3 clamp: output clamped to [0,1].
// With the MFMA emitting c = s*x + 0.5 (0.5 via C-operand), this single
// instruction IS the hard sigmoid.
__device__ inline h2 cvt_sig(float a, float b) {
    h2 d;
    asm("v_cvt_pkrtz_f16_f32 %0, %1, %2 clamp" : "=v"(d) : "v"(a), "v"(b));
    return d;
}

#define MFMA(A, B, C) __builtin_amdgcn_mfma_f32_32x32x16_bf16((A), (B), (C), 0, 0, 0)

// ---------------------------------------------------------------------------
// Phase 0: pre-pack weight MFMA A-fragments (96 blocks).
// wq/bq pre-scaled by the hard-sigmoid slope: sigma ~= clamp(s*x+0.5, 0, 1).
// ---------------------------------------------------------------------------
__global__ __launch_bounds__(256) void prep_kernel(
    const float* __restrict__ wq, const float* __restrict__ wk,
    const float* __restrict__ wv, const float* __restrict__ bq,
    u16* __restrict__ wfrag, float* __restrict__ bqs)
{
    const float QS = 0.21f;   // hard-sigmoid slope
    int idx = blockIdx.x * 256 + threadIdx.x;
    for (; idx < 3 * 2 * 16 * 64 * 8; idx += 96 * 256) {
        int j    = idx & 7;
        int lane = (idx >> 3) & 63;
        int s    = (idx >> 9) & 15;
        int ot   = (idx >> 13) & 1;
        int mat  = idx >> 14;
        int o = ot * 32 + (lane & 31);
        int c = s * 16 + (lane >> 5) * 8 + j;
        const float* wsrc = (mat == 0) ? wq : (mat == 1 ? wk : wv);
        float v = wsrc[o * CQ + c];
        if (mat == 0) v *= QS;
        wfrag[idx] = f2bf(v);
    }
    if (blockIdx.x == 0 && threadIdx.x < HD) bqs[threadIdx.x] = bq[threadIdx.x] * 0.21f;
}

// ---------------------------------------------------------------------------
// Phase 1: projections (unchanged, proven ~10us).
// ---------------------------------------------------------------------------
__global__ __launch_bounds__(512, 4) void proj_kernel(
    const float* __restrict__ x_q, const float* __restrict__ x_kv,
    const u16* __restrict__ wfrag, const float* __restrict__ bqs,
    const float* __restrict__ bk, const float* __restrict__ bv,
    u16* __restrict__ qb, u16* __restrict__ kb, u16* __restrict__ vb)
{
    __shared__ __align__(16) u32 xs[2 * 32 * 128];   // 32 KB
    const int tid = threadIdx.x;
    const int b   = blockIdx.x >> 7;
    const int wt  = blockIdx.x & 127;
    const int w0  = wt * 32;

    #pragma unroll
    for (int k = 0; k < 16; ++k) {
        int i  = k * 512 + tid;
        int m  = i >> 12;
        int r  = i & 4095;
        int cp = r >> 5;              // c-pair 0..127
        int w  = r & 31;              // lanes -> consecutive w: coalesced
        const float* src = (m ? x_kv : x_q) + ((size_t)b * CQ + 2 * cp) * W + w0 + w;
        float x0 = src[0];
        float x1 = src[W];
        xs[m * 4096 + w * 128 + (cp ^ ((w & 7) << 2))] = pkbf(x0, x1);
    }
    __syncthreads();

    const int wv_ = tid >> 6;
    if (wv_ < 6) {
        const int lane = tid & 63;
        const int mat  = wv_ >> 1;          // 0 q, 1 k, 2 v
        const int ot   = wv_ & 1;
        const int n    = lane & 31;
        const int khi  = lane >> 5;
        const int m    = (mat == 0) ? 0 : 1;

        const u16* wfp  = wfrag + (((size_t)(mat * 2 + ot) * 16) * 64 + lane) * 8;
        const u32* xrow = xs + m * 4096 + n * 128;
        const int  swz  = (n & 7) << 2;

        const f32x16 z = {0,0,0,0,0,0,0,0,0,0,0,0,0,0,0,0};
        f32x16 acc0 = z, acc1 = z;
        #pragma unroll
        for (int s = 0; s < 16; ++s) {
            const bf16x8 af = *(const bf16x8*)(wfp + s * 512);
            const int cp0 = s * 8 + khi * 4;
            const bf16x8 bf = *(const bf16x8*)(xrow + (cp0 ^ swz));
            if (s & 1) acc1 = MFMA(af, bf, acc1);
            else       acc0 = MFMA(af, bf, acc0);
        }

        const float* bias = (mat == 0) ? bqs : (mat == 1 ? bk : bv);
        u16* dst = (mat == 0) ? qb : (mat == 1 ? kb : vb);
        #pragma unroll
        for (int q = 0; q < 4; ++q) {
            int ob = ot * 32 + 8 * q + 4 * khi;
            float v0 = acc0[4 * q + 0] + acc1[4 * q + 0] + bias[ob + 0];
            float v1 = acc0[4 * q + 1] + acc1[4 * q + 1] + bias[ob + 1];
            float v2 = acc0[4 * q + 2] + acc1[4 * q + 2] + bias[ob + 2];
            float v3 = acc0[4 * q + 3] + acc1[4 * q + 3] + bias[ob + 3];
            int h = ob >> 4, d = ob & 15;
            uint2 pk = make_uint2(pkbf(v0, v1), pkbf(v2, v3));
            *(uint2*)(dst + ((size_t)(b * NH + h) * W + w0 + n) * DK + d) = pk;
        }
    }
}

// ---------------------------------------------------------------------------
// Phase 2: g[k] = sum_q sigma(q.k) fused with partial S = sum_k g[k]*v[k].
// MFMA C-operand carries the +0.5 (free); hard sigmoid collapses into
// v_cvt_pkrtz_f16_f32+clamp. Per pair: cvt + fdot2 = 2 insts (R15 was 3).
// R15 grid shape: 2048 blocks x 4 waves x 32 iters, single k-tile/wave.
// ---------------------------------------------------------------------------
__global__ __launch_bounds__(256, 4) void logits_kernel(
    const u16* __restrict__ qb, const u16* __restrict__ kb,
    const u16* __restrict__ vb, float* __restrict__ Spart)
{
    __shared__ float red[4][16];
    const int tid  = threadIdx.x;
    const int wv_  = tid >> 6;
    const int lane = tid & 63;
    const int bh   = blockIdx.x >> 7;
    const int rest = blockIdx.x & 127;   // ktg(0..31) + 32*qs(0..3)
    const int ktg  = rest & 31;
    const int qs   = rest >> 5;
    const int kt   = ktg * 4 + wv_;
    const int r    = lane & 31;
    const int d8   = (lane >> 5) * 8;

    const bf16x8 bfrag =
        *(const bf16x8*)(kb + (((size_t)bh * W + kt * 32 + r) * DK + d8));
    const u16* qp = qb + (((size_t)bh * W + qs * 1024 + r) * DK + d8);

    const f32x16 CH = {0.5f,0.5f,0.5f,0.5f,0.5f,0.5f,0.5f,0.5f,
                       0.5f,0.5f,0.5f,0.5f,0.5f,0.5f,0.5f,0.5f};
    const h2 ONE = {(__fp16)1.0f, (__fp16)1.0f};

    float accA = 0.f, accB = 0.f, accC = 0.f, accD = 0.f;

    #pragma unroll 4
    for (int it = 0; it < 32; ++it) {
        bf16x8 a = *(const bf16x8*)(qp + (size_t)it * 32 * DK);
        f32x16 c = MFMA(a, bfrag, CH);      // c = s*x + 0.5
        #pragma unroll
        for (int p2 = 0; p2 < 8; ++p2) {
            h2 sg = cvt_sig(c[2 * p2], c[2 * p2 + 1]);   // clamp -> sigma
            switch (p2 & 3) {
                case 0: accA = __builtin_amdgcn_fdot2(sg, ONE, accA, false); break;
                case 1: accB = __builtin_amdgcn_fdot2(sg, ONE, accB, false); break;
                case 2: accC = __builtin_amdgcn_fdot2(sg, ONE, accC, false); break;
                default: accD = __builtin_amdgcn_fdot2(sg, ONE, accD, false); break;
            }
        }
    }
    float g = (accA + accB) + (accC + accD);
    g += __shfl_xor(g, 32, 64);   // combine the two q-row halves of the column

    bf16x8 v8 = *(const bf16x8*)(vb + (((size_t)bh * W + kt * 32 + r) * DK + d8));
    float p[8];
    #pragma unroll
    for (int j = 0; j < 8; ++j) p[j] = g * bf2f((u16)v8[j]);
    #pragma unroll
    for (int m = 1; m < 32; m <<= 1) {
        #pragma unroll
        for (int j = 0; j < 8; ++j) p[j] += __shfl_xor(p[j], m, 64);
    }
    if (r == 0) {
        #pragma unroll
        for (int j = 0; j < 8; ++j) red[wv_][d8 + j] = p[j];
    }
    __syncthreads();
    if (tid < 16) {
        float s = (red[0][tid] + red[1][tid]) + (red[2][tid] + red[3][tid]);
        Spart[((size_t)bh * 128 + rest) * 16 + tid] = s;
    }
}

// ---------------------------------------------------------------------------
// Phase 3: reduce Spart (128 partials/bh), scale, output conv. 64 blocks.
// ---------------------------------------------------------------------------
__global__ __launch_bounds__(256) void out_kernel(
    const float* __restrict__ Spart, const float* __restrict__ wo,
    const float* __restrict__ bo, float* __restrict__ out)
{
    __shared__ float red[4][HD];
    __shared__ float pooled[HD];
    const int b  = blockIdx.x >> 4;
    const int og = blockIdx.x & 15;
    const int t  = threadIdx.x;
    const int hd = t & 63;       // (h,d) pair
    const int sg = t >> 6;       // partial segment 0..3
    const int h  = hd >> 4, d = hd & 15;

    const float* sp = Spart + (((size_t)(b * NH + h) * 128) + sg * 32) * 16 + d;
    float s = 0.f;
    #pragma unroll
    for (int i = 0; i < 32; ++i) s += sp[i * 16];
    red[sg][hd] = s;
    __syncthreads();
    if (t < HD)
        pooled[t] = (red[0][t] + red[1][t] + red[2][t] + red[3][t]) *
                    (1.f / ((float)W * (float)W));
    __syncthreads();
    if (t < 16) {
        int o = og * 16 + t;
        float val = bo[o];
        #pragma unroll
        for (int c2 = 0; c2 < HD; ++c2)
            val += wo[o * HD + c2] * pooled[c2];
        out[b * CQ + o] = val;
    }
}

extern "C" void kernel_launch(void* const* d_in, const int* in_sizes, int n_in,
                              void* d_out, int out_size, void* d_ws, size_t ws_size,
                              hipStream_t stream) {
    const float* x_q  = (const float*)d_in[0];
    const float* x_kv = (const float*)d_in[1];
    const float* wq   = (const float*)d_in[2];
    const float* bq   = (const float*)d_in[3];
    const float* wk   = (const float*)d_in[4];
    const float* bk   = (const float*)d_in[5];
    const float* wv   = (const float*)d_in[6];
    const float* bv   = (const float*)d_in[7];
    const float* wo   = (const float*)d_in[8];
    const float* bo   = (const float*)d_in[9];
    float* out = (float*)d_out;

    char* ws = (char*)d_ws;
    u16*   qb    = (u16*)ws;                              // 2 MB
    u16*   kb    = (u16*)(ws + (2u << 20));               // 2 MB
    u16*   vb    = (u16*)(ws + (4u << 20));               // 2 MB (bf16 V)
    float* Spart = (float*)(ws + (6u << 20));             // 128 KB
    u16*   wfrag = (u16*)(ws + (6u << 20) + (256u << 10));// 96 KB
    float* bqs   = (float*)(ws + (6u << 20) + (384u << 10));

    prep_kernel<<<96, 256, 0, stream>>>(wq, wk, wv, bq, wfrag, bqs);
    proj_kernel<<<512, 512, 0, stream>>>(x_q, x_kv, wfrag, bqs, bk, bv, qb, kb, vb);
    logits_kernel<<<2048, 256, 0, stream>>>(qb, kb, vb, Spart);
    out_kernel<<<BN * 16, 256, 0, stream>>>(Spart, wo, bo, out);
}

// Round 19
// 38.741 us; speedup vs baseline: 1.0937x; 1.0010x over previous
//
#include <hip/hip_runtime.h>

#define NH 4
#define DK 16
#define HD 64
#define CQ 256
#define W 4096
#define BN 4

typedef unsigned short u16;
typedef unsigned int u32;
typedef __attribute__((ext_vector_type(8))) short bf16x8;
typedef __attribute__((ext_vector_type(4))) float f32x4;
typedef __attribute__((ext_vector_type(16))) float f32x16;
typedef __fp16 h2 __attribute__((ext_vector_type(2)));

__device__ inline u32 pkbf(float a, float b) {
    u32 r;
    asm("v_cvt_pk_bf16_f32 %0, %1, %2" : "=v"(r) : "v"(a), "v"(b));
    return r;
}
__device__ inline float bf2f(u16 h) { return __uint_as_float(((unsigned)h) << 16); }
__device__ inline u16 f2bf(float f) {
    unsigned int u = __float_as_uint(f);
    return (u16)((u + 0x7FFFu + ((u >> 16) & 1u)) >> 16);
}
// f32 pair -> f16 pair with VOP3 clamp to [0,1]. With the MFMA emitting
// c = s*x + 0.5 (0.5 via C-operand), this single instruction IS the sigmoid.
__device__ inline h2 cvt_sig(float a, float b) {
    h2 d;
    asm("v_cvt_pkrtz_f16_f32 %0, %1, %2 clamp" : "=v"(d) : "v"(a), "v"(b));
    return d;
}

#define MFMA(A, B, C) __builtin_amdgcn_mfma_f32_32x32x16_bf16((A), (B), (C), 0, 0, 0)

// ---------------------------------------------------------------------------
// Phase 0: pre-pack weight MFMA A-fragments (96 blocks).
// wq/bq pre-scaled by the hard-sigmoid slope: sigma ~= clamp(s*x+0.5, 0, 1).
// ---------------------------------------------------------------------------
__global__ __launch_bounds__(256) void prep_kernel(
    const float* __restrict__ wq, const float* __restrict__ wk,
    const float* __restrict__ wv, const float* __restrict__ bq,
    u16* __restrict__ wfrag, float* __restrict__ bqs)
{
    const float QS = 0.21f;   // hard-sigmoid slope
    int idx = blockIdx.x * 256 + threadIdx.x;
    for (; idx < 3 * 2 * 16 * 64 * 8; idx += 96 * 256) {
        int j    = idx & 7;
        int lane = (idx >> 3) & 63;
        int s    = (idx >> 9) & 15;
        int ot   = (idx >> 13) & 1;
        int mat  = idx >> 14;
        int o = ot * 32 + (lane & 31);
        int c = s * 16 + (lane >> 5) * 8 + j;
        const float* wsrc = (mat == 0) ? wq : (mat == 1 ? wk : wv);
        float v = wsrc[o * CQ + c];
        if (mat == 0) v *= QS;
        wfrag[idx] = f2bf(v);
    }
    if (blockIdx.x == 0 && threadIdx.x < HD) bqs[threadIdx.x] = bq[threadIdx.x] * 0.21f;
}

// ---------------------------------------------------------------------------
// Phase 1: projections (unchanged, proven ~10us).
// ---------------------------------------------------------------------------
__global__ __launch_bounds__(512, 4) void proj_kernel(
    const float* __restrict__ x_q, const float* __restrict__ x_kv,
    const u16* __restrict__ wfrag, const float* __restrict__ bqs,
    const float* __restrict__ bk, const float* __restrict__ bv,
    u16* __restrict__ qb, u16* __restrict__ kb, u16* __restrict__ vb)
{
    __shared__ __align__(16) u32 xs[2 * 32 * 128];   // 32 KB
    const int tid = threadIdx.x;
    const int b   = blockIdx.x >> 7;
    const int wt  = blockIdx.x & 127;
    const int w0  = wt * 32;

    #pragma unroll
    for (int k = 0; k < 16; ++k) {
        int i  = k * 512 + tid;
        int m  = i >> 12;
        int r  = i & 4095;
        int cp = r >> 5;              // c-pair 0..127
        int w  = r & 31;              // lanes -> consecutive w: coalesced
        const float* src = (m ? x_kv : x_q) + ((size_t)b * CQ + 2 * cp) * W + w0 + w;
        float x0 = src[0];
        float x1 = src[W];
        xs[m * 4096 + w * 128 + (cp ^ ((w & 7) << 2))] = pkbf(x0, x1);
    }
    __syncthreads();

    const int wv_ = tid >> 6;
    if (wv_ < 6) {
        const int lane = tid & 63;
        const int mat  = wv_ >> 1;          // 0 q, 1 k, 2 v
        const int ot   = wv_ & 1;
        const int n    = lane & 31;
        const int khi  = lane >> 5;
        const int m    = (mat == 0) ? 0 : 1;

        const u16* wfp  = wfrag + (((size_t)(mat * 2 + ot) * 16) * 64 + lane) * 8;
        const u32* xrow = xs + m * 4096 + n * 128;
        const int  swz  = (n & 7) << 2;

        const f32x16 z = {0,0,0,0,0,0,0,0,0,0,0,0,0,0,0,0};
        f32x16 acc0 = z, acc1 = z;
        #pragma unroll
        for (int s = 0; s < 16; ++s) {
            const bf16x8 af = *(const bf16x8*)(wfp + s * 512);
            const int cp0 = s * 8 + khi * 4;
            const bf16x8 bf = *(const bf16x8*)(xrow + (cp0 ^ swz));
            if (s & 1) acc1 = MFMA(af, bf, acc1);
            else       acc0 = MFMA(af, bf, acc0);
        }

        const float* bias = (mat == 0) ? bqs : (mat == 1 ? bk : bv);
        u16* dst = (mat == 0) ? qb : (mat == 1 ? kb : vb);
        #pragma unroll
        for (int q = 0; q < 4; ++q) {
            int ob = ot * 32 + 8 * q + 4 * khi;
            float v0 = acc0[4 * q + 0] + acc1[4 * q + 0] + bias[ob + 0];
            float v1 = acc0[4 * q + 1] + acc1[4 * q + 1] + bias[ob + 1];
            float v2 = acc0[4 * q + 2] + acc1[4 * q + 2] + bias[ob + 2];
            float v3 = acc0[4 * q + 3] + acc1[4 * q + 3] + bias[ob + 3];
            int h = ob >> 4, d = ob & 15;
            uint2 pk = make_uint2(pkbf(v0, v1), pkbf(v2, v3));
            *(uint2*)(dst + ((size_t)(b * NH + h) * W + w0 + n) * DK + d) = pk;
        }
    }
}

// ---------------------------------------------------------------------------
// Phase 2: g[k] = sum_q sigma(q.k) fused with partial S = sum_k g[k]*v[k].
// MFMA C-operand carries the +0.5 (free); hard sigmoid collapses into
// v_cvt_pkrtz_f16_f32+clamp. Per pair: cvt + fdot2 = 2 insts.
// 2048 blocks x 4 waves x 32 iters, single k-tile/wave (R17 proven shape;
// the 64-iter variant miscompiled - R18 postmortem).
// ---------------------------------------------------------------------------
__global__ __launch_bounds__(256, 4) void logits_kernel(
    const u16* __restrict__ qb, const u16* __restrict__ kb,
    const u16* __restrict__ vb, float* __restrict__ Spart)
{
    __shared__ float red[4][16];
    const int tid  = threadIdx.x;
    const int wv_  = tid >> 6;
    const int lane = tid & 63;
    const int bh   = blockIdx.x >> 7;
    const int rest = blockIdx.x & 127;   // ktg(0..31) + 32*qs(0..3)
    const int ktg  = rest & 31;
    const int qs   = rest >> 5;
    const int kt   = ktg * 4 + wv_;
    const int r    = lane & 31;
    const int d8   = (lane >> 5) * 8;

    const bf16x8 bfrag =
        *(const bf16x8*)(kb + (((size_t)bh * W + kt * 32 + r) * DK + d8));
    const u16* qp = qb + (((size_t)bh * W + qs * 1024 + r) * DK + d8);

    const f32x16 CH = {0.5f,0.5f,0.5f,0.5f,0.5f,0.5f,0.5f,0.5f,
                       0.5f,0.5f,0.5f,0.5f,0.5f,0.5f,0.5f,0.5f};
    const h2 ONE = {(__fp16)1.0f, (__fp16)1.0f};

    float accA = 0.f, accB = 0.f, accC = 0.f, accD = 0.f;

    #pragma unroll 4
    for (int it = 0; it < 32; ++it) {
        bf16x8 a = *(const bf16x8*)(qp + (size_t)it * 32 * DK);
        f32x16 c = MFMA(a, bfrag, CH);      // c = s*x + 0.5
        #pragma unroll
        for (int p2 = 0; p2 < 8; ++p2) {
            h2 sg = cvt_sig(c[2 * p2], c[2 * p2 + 1]);   // clamp -> sigma
            switch (p2 & 3) {
                case 0: accA = __builtin_amdgcn_fdot2(sg, ONE, accA, false); break;
                case 1: accB = __builtin_amdgcn_fdot2(sg, ONE, accB, false); break;
                case 2: accC = __builtin_amdgcn_fdot2(sg, ONE, accC, false); break;
                default: accD = __builtin_amdgcn_fdot2(sg, ONE, accD, false); break;
            }
        }
    }
    float g = (accA + accB) + (accC + accD);
    g += __shfl_xor(g, 32, 64);   // combine the two q-row halves of the column

    bf16x8 v8 = *(const bf16x8*)(vb + (((size_t)bh * W + kt * 32 + r) * DK + d8));
    float p[8];
    #pragma unroll
    for (int j = 0; j < 8; ++j) p[j] = g * bf2f((u16)v8[j]);
    #pragma unroll
    for (int m = 1; m < 32; m <<= 1) {
        #pragma unroll
        for (int j = 0; j < 8; ++j) p[j] += __shfl_xor(p[j], m, 64);
    }
    if (r == 0) {
        #pragma unroll
        for (int j = 0; j < 8; ++j) red[wv_][d8 + j] = p[j];
    }
    __syncthreads();
    if (tid < 16) {
        float s = (red[0][tid] + red[1][tid]) + (red[2][tid] + red[3][tid]);
        Spart[((size_t)bh * 128 + rest) * 16 + tid] = s;
    }
}

// ---------------------------------------------------------------------------
// Phase 3: reduce Spart (128 partials/bh), scale, output conv. 64 blocks.
// ---------------------------------------------------------------------------
__global__ __launch_bounds__(256) void out_kernel(
    const float* __restrict__ Spart, const float* __restrict__ wo,
    const float* __restrict__ bo, float* __restrict__ out)
{
    __shared__ float red[4][HD];
    __shared__ float pooled[HD];
    const int b  = blockIdx.x >> 4;
    const int og = blockIdx.x & 15;
    const int t  = threadIdx.x;
    const int hd = t & 63;       // (h,d) pair
    const int sg = t >> 6;       // partial segment 0..3
    const int h  = hd >> 4, d = hd & 15;

    const float* sp = Spart + (((size_t)(b * NH + h) * 128) + sg * 32) * 16 + d;
    float s = 0.f;
    #pragma unroll
    for (int i = 0; i < 32; ++i) s += sp[i * 16];
    red[sg][hd] = s;
    __syncthreads();
    if (t < HD)
        pooled[t] = (red[0][t] + red[1][t] + red[2][t] + red[3][t]) *
                    (1.f / ((float)W * (float)W));
    __syncthreads();
    if (t < 16) {
        int o = og * 16 + t;
        float val = bo[o];
        #pragma unroll
        for (int c2 = 0; c2 < HD; ++c2)
            val += wo[o * HD + c2] * pooled[c2];
        out[b * CQ + o] = val;
    }
}

extern "C" void kernel_launch(void* const* d_in, const int* in_sizes, int n_in,
                              void* d_out, int out_size, void* d_ws, size_t ws_size,
                              hipStream_t stream) {
    const float* x_q  = (const float*)d_in[0];
    const float* x_kv = (const float*)d_in[1];
    const float* wq   = (const float*)d_in[2];
    const float* bq   = (const float*)d_in[3];
    const float* wk   = (const float*)d_in[4];
    const float* bk   = (const float*)d_in[5];
    const float* wv   = (const float*)d_in[6];
    const float* bv   = (const float*)d_in[7];
    const float* wo   = (const float*)d_in[8];
    const float* bo   = (const float*)d_in[9];
    float* out = (float*)d_out;

    char* ws = (char*)d_ws;
    u16*   qb    = (u16*)ws;                              // 2 MB
    u16*   kb    = (u16*)(ws + (2u << 20));               // 2 MB
    u16*   vb    = (u16*)(ws + (4u << 20));               // 2 MB (bf16 V)
    float* Spart = (float*)(ws + (6u << 20));             // 128 KB
    u16*   wfrag = (u16*)(ws + (6u << 20) + (256u << 10));// 96 KB
    float* bqs   = (float*)(ws + (6u << 20) + (384u << 10));

    prep_kernel<<<96, 256, 0, stream>>>(wq, wk, wv, bq, wfrag, bqs);
    proj_kernel<<<512, 512, 0, stream>>>(x_q, x_kv, wfrag, bqs, bk, bv, qb, kb, vb);
    logits_kernel<<<2048, 256, 0, stream>>>(qb, kb, vb, Spart);
    out_kernel<<<BN * 16, 256, 0, stream>>>(Spart, wo, bo, out);
}